// Round 1
// baseline (418.209 us; speedup 1.0000x reference)
//
#include <hip/hip_runtime.h>
#include <cmath>

// Problem constants
constexpr int NBATCH  = 32;
constexpr int NSEQ    = 4096;
constexpr int NCH     = 128;           // channels = rows per batch
constexpr int NEXP    = 64;            // experts
constexpr int NE2     = 128;           // main + noise logits per row
constexpr int DIN     = 2 * NSEQ;      // 8192
constexpr int ROWS    = NBATCH * NCH;  // 4096

// GEMM tiling
constexpr int KCH     = 16;            // split-K chunks
constexpr int S_CHUNK = NSEQ / KCH;    // 256 s per block
constexpr int SS      = 16;            // s per sub-iteration
constexpr int FS      = SS * 2;        // 32 features per sub-iteration
constexpr int NSUB    = S_CHUNK / SS;  // 16 sub-iterations
constexpr int XPAD    = NCH + 4;       // 132 (2-way on writes, 2-way on f4 reads)
constexpr int WPAD    = NE2 + 4;       // 132 (conflict-free f4 reads)

// Kernel 1: partial GEMM. Block = 256 thr computes 128c x 128e tile for one
// (batch, k-chunk); writes partials[kc][row][e] (each element written once).
__global__ __launch_bounds__(256, 2)
void gemm_partial_kernel(const float* __restrict__ x,
                         const float* __restrict__ Wm,
                         const float* __restrict__ Wn,
                         float* __restrict__ partials)
{
    const int kc  = blockIdx.x;
    const int b   = blockIdx.y;
    const int tid = threadIdx.x;
    const int tc  = tid & 15;    // 16 c-groups
    const int te  = tid >> 4;    // 16 e-groups

    __shared__ float xs[FS][XPAD];   // [32][132]  x tile, [f][c]
    __shared__ float ws[FS][WPAD];   // [32][132]  W tile, [f][e] (transposed)

    float acc[8][8];
#pragma unroll
    for (int i = 0; i < 8; ++i)
#pragma unroll
        for (int j = 0; j < 8; ++j) acc[i][j] = 0.f;

    const int s0 = kc * S_CHUNK;
    // x memory layout: x[((b*NSEQ + s)*NCH + c)*2 + t]; one s-plane = 256 contiguous floats
    const float* xbase = x + (size_t)b * NSEQ * 256;

    for (int ss = 0; ss < NSUB; ++ss) {
        const int sb = s0 + ss * SS;
        // ---- stage x: SS s-planes of 256 contiguous floats (coalesced) ----
#pragma unroll
        for (int r = 0; r < SS; ++r) {
            float v = xbase[(size_t)(sb + r) * 256 + tid];
            // u = tid = c*2 + t ; f_local = 2r + t
            xs[r * 2 + (tid & 1)][tid >> 1] = v;   // 2-way bank alias: free
        }
        // ---- stage W: 128 e x 32 f, transposed to ws[f][e] ----
        const int fb = sb * 2;
#pragma unroll
        for (int r = 0; r < 16; ++r) {
            int idx = r * 256 + tid;
            int f = idx & 31;
            int e = idx >> 5;           // wave-uniform branch (boundary is 64-aligned)
            const float* wsrc = (e < NEXP) ? (Wm + (size_t)e * DIN)
                                           : (Wn + (size_t)(e - NEXP) * DIN);
            ws[f][e] = wsrc[fb + f];    // coalesced 128B global runs
        }
        __syncthreads();

        // ---- microkernel: 8c x 8e outer product per thread ----
#pragma unroll 4
        for (int f = 0; f < FS; ++f) {
            const float4 x0 = *(const float4*)&xs[f][tc * 4];        // c = tc*4..+3
            const float4 x1 = *(const float4*)&xs[f][64 + tc * 4];   // c = 64+tc*4..+3
            const float4 w0 = *(const float4*)&ws[f][te * 8];        // e = te*8..+3
            const float4 w1 = *(const float4*)&ws[f][te * 8 + 4];    // e = te*8+4..+7
            float xr[8] = {x0.x, x0.y, x0.z, x0.w, x1.x, x1.y, x1.z, x1.w};
            float wr[8] = {w0.x, w0.y, w0.z, w0.w, w1.x, w1.y, w1.z, w1.w};
#pragma unroll
            for (int i = 0; i < 8; ++i)
#pragma unroll
                for (int j = 0; j < 8; ++j)
                    acc[i][j] = fmaf(xr[i], wr[j], acc[i][j]);
        }
        __syncthreads();
    }

    // ---- epilogue: write partial tile (float4 stores) ----
    float* outp = partials + ((size_t)kc * ROWS + (size_t)b * NCH) * NE2;
#pragma unroll
    for (int half = 0; half < 2; ++half)
#pragma unroll
        for (int i = 0; i < 4; ++i) {
            int c  = half * 64 + tc * 4 + i;
            int ai = half * 4 + i;
            float4 s0 = make_float4(acc[ai][0], acc[ai][1], acc[ai][2], acc[ai][3]);
            float4 s1 = make_float4(acc[ai][4], acc[ai][5], acc[ai][6], acc[ai][7]);
            *(float4*)&outp[(size_t)c * NE2 + te * 8]     = s0;
            *(float4*)&outp[(size_t)c * NE2 + te * 8 + 4] = s1;
        }
}

// Kernel 2: reduce split-K partials, bias, softplus, exact top-2 keep
// (kthvalue semantics incl. duplicates), masked softmax. One wave per row.
__global__ void gate_kernel(const float* __restrict__ partials,
                            const float* __restrict__ bm,
                            const float* __restrict__ bn,
                            float* __restrict__ out)
{
    const int row  = blockIdx.x;
    const int lane = threadIdx.x;   // 0..63 <-> expert id

    float m  = bm[lane];
    float nz = bn[lane];
    const float* p = partials + (size_t)row * NE2 + lane;
#pragma unroll
    for (int kc = 0; kc < KCH; ++kc) {
        const float* q = p + (size_t)kc * ROWS * NE2;
        m  += q[0];      // main logit partial (e = lane)
        nz += q[NEXP];   // noise logit partial (e = 64 + lane)
    }
    // softplus = logaddexp(nz, 0), numerically stable
    float sp = fmaxf(nz, 0.f) + log1pf(expf(-fabsf(nz)));
    float g  = m + sp;

    // kth = 3rd largest (with multiplicity) = sorted_asc[61]
    float v  = g;
    float m1 = v;
#pragma unroll
    for (int o = 32; o > 0; o >>= 1) m1 = fmaxf(m1, __shfl_xor(m1, o));
    unsigned long long b1 = __ballot(v == m1);
    int l1 = __ffsll(b1) - 1;
    if (lane == l1) v = -INFINITY;          // remove one instance of max
    float m2 = v;
#pragma unroll
    for (int o = 32; o > 0; o >>= 1) m2 = fmaxf(m2, __shfl_xor(m2, o));
    unsigned long long b2 = __ballot(v == m2);
    int l2 = __ffsll(b2) - 1;
    if (lane == l2) v = -INFINITY;          // remove one instance of 2nd
    float kth = v;
#pragma unroll
    for (int o = 32; o > 0; o >>= 1) kth = fmaxf(kth, __shfl_xor(kth, o));

    // softmax over {g > kth}; max of kept set is m1
    float ev  = (g > kth) ? expf(g - m1) : 0.f;
    float den = ev;
#pragma unroll
    for (int o = 32; o > 0; o >>= 1) den += __shfl_xor(den, o);
    out[(size_t)row * NEXP + lane] = ev / den;
}

extern "C" void kernel_launch(void* const* d_in, const int* in_sizes, int n_in,
                              void* d_out, int out_size, void* d_ws, size_t ws_size,
                              hipStream_t stream)
{
    const float* x  = (const float*)d_in[0];
    const float* Wm = (const float*)d_in[1];
    const float* bm = (const float*)d_in[2];
    const float* Wn = (const float*)d_in[3];
    const float* bn = (const float*)d_in[4];
    float* out      = (float*)d_out;
    float* partials = (float*)d_ws;   // needs KCH*ROWS*NE2*4 = 32 MB; fully overwritten

    dim3 g1(KCH, NBATCH);             // 512 blocks, 2 per CU
    gemm_partial_kernel<<<g1, 256, 0, stream>>>(x, Wm, Wn, partials);
    gate_kernel<<<ROWS, 64, 0, stream>>>(partials, bm, bn, out);
}

// Round 2
// 211.925 us; speedup vs baseline: 1.9734x; 1.9734x over previous
//
#include <hip/hip_runtime.h>
#include <cmath>

typedef _Float16 f16x8 __attribute__((ext_vector_type(8)));
typedef _Float16 f16x4 __attribute__((ext_vector_type(4)));
typedef float    f32x16 __attribute__((ext_vector_type(16)));

constexpr int NBATCH = 32;
constexpr int NSEQ   = 4096;
constexpr int NCH    = 128;
constexpr int NEXP   = 64;
constexpr int NE2    = 128;
constexpr int DIN    = 2 * NSEQ;       // 8192
constexpr int ROWS   = NBATCH * NCH;   // 4096
constexpr int KCH    = 16;             // split-K chunks (512 features each)
constexpr float LOSC = 2048.0f;        // lo-term scale (2^11)
constexpr float INV_LOSC = 1.0f / 2048.0f;

// LDS tile: [row 128][k 64] f16, XOR-swizzled (G4: row-stride 128B would be a
// 32..64-way bank conflict on b128 ops; XOR of hw bits 3-5 with row&7 makes
// every 64-lane b128 access cover all 32 banks uniformly = optimal 8-cycle).
#define SWZ(row, k) ((((row) * 64) + (k)) ^ (((row) & 7) << 3))

// ---------------------------------------------------------------------------
// Kernel 1: split-f16 MFMA partial GEMM.
// Grid (kc=16, b=32). Block 256 thr = 4 waves (2x2), tile M=128(c) x N=128(e),
// K-chunk = 512 features. acc1 = hi*hi ; acc2 = hi*lo + lo*hi (lo pre-scaled
// by 2048). out = acc1 + acc2/2048.
// ---------------------------------------------------------------------------
__global__ __launch_bounds__(256, 2)
void gemm_kernel(const float* __restrict__ x,
                 const float* __restrict__ Wm,
                 const float* __restrict__ Wn,
                 float* __restrict__ partials)
{
    const int kc   = blockIdx.x;
    const int b    = blockIdx.y;
    const int tid  = threadIdx.x;
    const int lane = tid & 63;
    const int wave = tid >> 6;
    const int wm   = wave >> 1;   // 2 wave-rows
    const int wn   = wave & 1;    // 2 wave-cols

    __shared__ _Float16 lds[4 * 8192];       // 64 KiB
    _Float16* Ah = lds;                      // x hi   [128][64]
    _Float16* Al = lds + 8192;               // x lo
    _Float16* Bh = lds + 16384;              // W hi
    _Float16* Bl = lds + 24576;              // W lo

    f32x16 acc1[2][2], acc2[2][2];
#pragma unroll
    for (int mi = 0; mi < 2; ++mi)
#pragma unroll
        for (int ni = 0; ni < 2; ++ni)
#pragma unroll
            for (int r = 0; r < 16; ++r) { acc1[mi][ni][r] = 0.f; acc2[mi][ni][r] = 0.f; }

    // x chunk: s in [kc*256, kc*256+256), contiguous 256 KB
    const float* xchunk = x + (size_t)b * (NSEQ * 256) + (size_t)kc * 256 * 256;
    const int fb = kc * 512;

    float2 xr[16];   // per-sub-iter x stage: 32 floats (c=tid&127, 4 k-octets)
    auto load_x = [&](int ss) {
        const float* bp = xchunk + ss * 8192;   // 32 s-planes x 256 floats
#pragma unroll
        for (int u = 0; u < 4; ++u) {
            const int kg = u * 2 + (tid >> 7);  // k-octet 0..7
#pragma unroll
            for (int j = 0; j < 4; ++j)         // 4 s-planes per octet
                xr[u * 4 + j] = *(const float2*)(bp + (kg * 4 + j) * 256 + (tid & 127) * 2);
        }
    };

    load_x(0);

    for (int ss = 0; ss < 8; ++ss) {
        // W loads to regs (issue before barrier so they fly during prev MFMA)
        float4 wr[8];
#pragma unroll
        for (int p = 0; p < 8; ++p) {
            const int e = p * 16 + (tid >> 4);           // wave-uniform vs 64
            const float* wsrc = (e < NEXP) ? (Wm + (size_t)e * DIN)
                                           : (Wn + (size_t)(e - NEXP) * DIN);
            wr[p] = *(const float4*)(wsrc + fb + ss * 64 + (tid & 15) * 4);
        }

        if (ss) __syncthreads();   // prev MFMA done reading LDS

        // ---- x -> split f16 -> LDS (b128 writes, swizzled) ----
#pragma unroll
        for (int u = 0; u < 4; ++u) {
            const int kg = u * 2 + (tid >> 7);
            const int c  = tid & 127;
            f16x8 hv, lv;
#pragma unroll
            for (int i = 0; i < 8; ++i) {
                float v = (i & 1) ? xr[u * 4 + (i >> 1)].y : xr[u * 4 + (i >> 1)].x;
                _Float16 h = (_Float16)v;
                hv[i] = h;
                lv[i] = (_Float16)((v - (float)h) * LOSC);
            }
            const int hw = SWZ(c, kg * 8);
            *(f16x8*)&Ah[hw] = hv;
            *(f16x8*)&Al[hw] = lv;
        }
        // ---- W -> split f16 -> LDS (b64 writes, swizzled) ----
#pragma unroll
        for (int p = 0; p < 8; ++p) {
            const int e = p * 16 + (tid >> 4);
            float vv[4] = { wr[p].x, wr[p].y, wr[p].z, wr[p].w };
            f16x4 hv, lv;
#pragma unroll
            for (int i = 0; i < 4; ++i) {
                _Float16 h = (_Float16)vv[i];
                hv[i] = h;
                lv[i] = (_Float16)((vv[i] - (float)h) * LOSC);
            }
            const int hw = SWZ(e, (tid & 15) * 4);
            *(f16x4*)&Bh[hw] = hv;
            *(f16x4*)&Bl[hw] = lv;
        }
        __syncthreads();

        if (ss < 7) load_x(ss + 1);   // prefetch next x during MFMA phase

        // ---- MFMA: 4 k-steps of 16 ----
#pragma unroll
        for (int kk = 0; kk < 4; ++kk) {
            const int ko = kk * 16 + (lane >> 5) * 8;
            f16x8 ah[2], al[2], bh[2], bl[2];
#pragma unroll
            for (int i = 0; i < 2; ++i) {
                const int ra = wm * 64 + i * 32 + (lane & 31);
                const int rb = wn * 64 + i * 32 + (lane & 31);
                ah[i] = *(const f16x8*)&Ah[SWZ(ra, ko)];
                al[i] = *(const f16x8*)&Al[SWZ(ra, ko)];
                bh[i] = *(const f16x8*)&Bh[SWZ(rb, ko)];
                bl[i] = *(const f16x8*)&Bl[SWZ(rb, ko)];
            }
#pragma unroll
            for (int mi = 0; mi < 2; ++mi)
#pragma unroll
                for (int ni = 0; ni < 2; ++ni) {
                    acc1[mi][ni] = __builtin_amdgcn_mfma_f32_32x32x16_f16(ah[mi], bh[ni], acc1[mi][ni], 0, 0, 0);
                    acc2[mi][ni] = __builtin_amdgcn_mfma_f32_32x32x16_f16(ah[mi], bl[ni], acc2[mi][ni], 0, 0, 0);
                    acc2[mi][ni] = __builtin_amdgcn_mfma_f32_32x32x16_f16(al[mi], bh[ni], acc2[mi][ni], 0, 0, 0);
                }
        }
    }

    // ---- epilogue: combine terms, write partials[kc][row][e] ----
    // C/D layout (m74/m101): col = lane&31, row = (reg&3) + 8*(reg>>2) + 4*(lane>>5)
    float* outp = partials + ((size_t)kc * ROWS + (size_t)b * NCH) * NE2;
#pragma unroll
    for (int mi = 0; mi < 2; ++mi)
#pragma unroll
        for (int ni = 0; ni < 2; ++ni)
#pragma unroll
            for (int r = 0; r < 16; ++r) {
                const int rloc = (r & 3) + 8 * (r >> 2) + 4 * (lane >> 5);
                const int crow = wm * 64 + mi * 32 + rloc;
                const int e    = wn * 64 + ni * 32 + (lane & 31);
                outp[(size_t)crow * NE2 + e] = acc1[mi][ni][r] + acc2[mi][ni][r] * INV_LOSC;
            }
}

// ---------------------------------------------------------------------------
// Kernel 2: reduce split-K partials, bias, softplus, exact top-2 keep
// (kthvalue semantics incl. duplicates), masked softmax.
// Block = 256 thr = 2 rows x 128 experts; noise wave hands softplus to main
// wave via LDS; top-k ballot runs wholly inside the main wave.
// ---------------------------------------------------------------------------
__global__ __launch_bounds__(256)
void gate_kernel(const float* __restrict__ partials,
                 const float* __restrict__ bm,
                 const float* __restrict__ bn,
                 float* __restrict__ out)
{
    const int tid  = threadIdx.x;
    const int rl   = tid >> 7;        // row_local 0..1
    const int e    = tid & 127;
    const int lane = tid & 63;
    const int row  = blockIdx.x * 2 + rl;

    const float* p = partials + (size_t)row * NE2 + e;
    float s = 0.f;
#pragma unroll
    for (int kc = 0; kc < KCH; ++kc)
        s += p[(size_t)kc * ROWS * NE2];

    __shared__ float spl[2][64];
    if (e >= NEXP) {   // noise wave
        float nz = s + bn[lane];
        spl[rl][lane] = fmaxf(nz, 0.f) + log1pf(expf(-fabsf(nz)));
    }
    __syncthreads();
    if (e < NEXP) {    // main wave
        float g = s + bm[lane] + spl[rl][lane];

        float v  = g;
        float m1 = v;
#pragma unroll
        for (int o = 32; o > 0; o >>= 1) m1 = fmaxf(m1, __shfl_xor(m1, o));
        unsigned long long b1 = __ballot(v == m1);
        int l1 = __ffsll(b1) - 1;
        if (lane == l1) v = -INFINITY;
        float m2 = v;
#pragma unroll
        for (int o = 32; o > 0; o >>= 1) m2 = fmaxf(m2, __shfl_xor(m2, o));
        unsigned long long b2 = __ballot(v == m2);
        int l2 = __ffsll(b2) - 1;
        if (lane == l2) v = -INFINITY;
        float kth = v;
#pragma unroll
        for (int o = 32; o > 0; o >>= 1) kth = fmaxf(kth, __shfl_xor(kth, o));

        float ev  = (g > kth) ? expf(g - m1) : 0.f;
        float den = ev;
#pragma unroll
        for (int o = 32; o > 0; o >>= 1) den += __shfl_xor(den, o);
        out[(size_t)row * NEXP + lane] = ev / den;
    }
}

extern "C" void kernel_launch(void* const* d_in, const int* in_sizes, int n_in,
                              void* d_out, int out_size, void* d_ws, size_t ws_size,
                              hipStream_t stream)
{
    const float* x  = (const float*)d_in[0];
    const float* Wm = (const float*)d_in[1];
    const float* bm = (const float*)d_in[2];
    const float* Wn = (const float*)d_in[3];
    const float* bn = (const float*)d_in[4];
    float* out      = (float*)d_out;
    float* partials = (float*)d_ws;   // 16*4096*128*4 = 32 MiB (proven fits ws)

    dim3 g1(KCH, NBATCH);             // 512 blocks, 2/CU
    gemm_kernel<<<g1, 256, 0, stream>>>(x, Wm, Wn, partials);
    gate_kernel<<<ROWS / 2, 256, 0, stream>>>(partials, bm, bn, out);
}

// Round 3
// 210.330 us; speedup vs baseline: 1.9883x; 1.0076x over previous
//
#include <hip/hip_runtime.h>
#include <cmath>

typedef _Float16 f16x8 __attribute__((ext_vector_type(8)));
typedef _Float16 f16x4 __attribute__((ext_vector_type(4)));
typedef float    f32x16 __attribute__((ext_vector_type(16)));

constexpr int NBATCH = 32;
constexpr int NSEQ   = 4096;
constexpr int NCH    = 128;
constexpr int NEXP   = 64;
constexpr int NE2    = 128;
constexpr int DIN    = 2 * NSEQ;       // 8192
constexpr int ROWS   = NBATCH * NCH;   // 4096
constexpr int KCH    = 16;             // split-K chunks (512 features each)
constexpr int KT     = 16;             // K-tiles per chunk (32 features each)
constexpr float LOSC = 2048.0f;
constexpr float INV_LOSC = 1.0f / 2048.0f;

// ws layout: partials 32 MiB @0 ; Whi 2 MiB @32Mi ; Wlo 2 MiB @34Mi
constexpr size_t WS_WHI = 32ull << 20;
constexpr size_t WS_WLO = 34ull << 20;

// [128][32] f16 tile, rows 64B: XOR 16B-granule with (row>>1)&3 so b128
// reads/writes by 32-row lane groups cover banks uniformly (G4; without it
// the 64B row stride is an 8-16-way conflict).
__device__ __forceinline__ int swz_f16(int row, int g) {
    return row * 32 + ((g ^ ((row >> 1) & 3)) << 3);
}

__device__ __forceinline__ void gload_lds16(const void* g, void* l) {
    __builtin_amdgcn_global_load_lds(
        (const __attribute__((address_space(1))) unsigned int*)g,
        (__attribute__((address_space(3))) unsigned int*)l, 16, 0, 0);
}

// ---------------------------------------------------------------------------
// Prep: split W (main ++ noise, 128 x 8192 f32) into f16 hi/lo, with the
// per-32f-tile granule swizzle PRE-BAKED so gemm can global_load_lds linearly.
// ---------------------------------------------------------------------------
__global__ __launch_bounds__(256)
void wprep_kernel(const float* __restrict__ Wm, const float* __restrict__ Wn,
                  _Float16* __restrict__ Whi, _Float16* __restrict__ Wlo)
{
    const int idx = (blockIdx.x * 256 + threadIdx.x) * 4;  // f32 index, 1M total
    const int row = idx >> 13;
    const int f   = idx & 8191;
    const float* src = (row < NEXP) ? (Wm + (size_t)row * DIN + f)
                                    : (Wn + (size_t)(row - NEXP) * DIN + f);
    const float4 v = *(const float4*)src;
    const int g  = (f >> 3) & 3;
    const int fs = (f & ~0x18) | ((g ^ ((row >> 1) & 3)) << 3);
    float vv[4] = { v.x, v.y, v.z, v.w };
    f16x4 h, l;
#pragma unroll
    for (int j = 0; j < 4; ++j) {
        _Float16 hj = (_Float16)vv[j];
        h[j] = hj;
        l[j] = (_Float16)((vv[j] - (float)hj) * LOSC);
    }
    *(f16x4*)&Whi[(size_t)row * 8192 + fs] = h;
    *(f16x4*)&Wlo[(size_t)row * 8192 + fs] = l;
}

// ---------------------------------------------------------------------------
// GEMM: split-f16 MFMA, 2-phase double-buffered pipeline.
// Grid 512 linear (bijective XCD swizzle -> (kc,b)); block 256 = 4 waves 2x2;
// tile M=128(c) x N=128(e), K-chunk 512 = 16 tiles of 32.
// acc1 = hi*hi ; acc2 = hi*lo + lo*hi ; out = acc1 + acc2/2048.
// ---------------------------------------------------------------------------
__global__ __launch_bounds__(256, 2)
void gemm_kernel(const float* __restrict__ x,
                 const _Float16* __restrict__ Whi,
                 const _Float16* __restrict__ Wlo,
                 float* __restrict__ partials)
{
    // XCD swizzle: each XCD gets kc in {x, x+8} for all 32 b -> W L2-resident
    const int l    = blockIdx.x;
    const int slot = l >> 3;
    const int kc   = (l & 7) + 8 * (slot & 1);
    const int b    = slot >> 1;

    const int tid  = threadIdx.x;
    const int lane = tid & 63;
    const int wave = tid >> 6;
    const int wm   = wave >> 1;
    const int wn   = wave & 1;

    __shared__ _Float16 lds[2 * 16384];   // 64 KiB: 2 bufs x {Ah,Al,Bh,Bl}[128][32]

    f32x16 acc1[2][2], acc2[2][2];
#pragma unroll
    for (int mi = 0; mi < 2; ++mi)
#pragma unroll
        for (int ni = 0; ni < 2; ++ni)
#pragma unroll
            for (int r = 0; r < 16; ++r) { acc1[mi][ni][r] = 0.f; acc2[mi][ni][r] = 0.f; }

    // x: ((b*4096 + s)*128 + c)*2 + t ; one s-plane = 256 contiguous f32
    const float* xchunk = x + (size_t)b * (NSEQ * 256) + (size_t)kc * (256 * 256);
    const int c    = tid & 127;      // channel (A-row)
    const int gsel = tid >> 7;       // this thread covers granules {gsel, 2+gsel}
    const int fb0  = kc * 512;

    // W gload lane addressing: lane -> e = e0 + (lane>>2), 16B granule lane&3
    const int e_ld = lane >> 2;
    const int goff = (lane & 3) * 8;

    float2 xr[8];
    auto load_x = [&](int t) {
#pragma unroll
        for (int u = 0; u < 2; ++u) {
            const int g = u * 2 + gsel;
#pragma unroll
            for (int i = 0; i < 4; ++i)   // planes 4g..4g+3 give k=8g..8g+7
                xr[u * 4 + i] = *(const float2*)(xchunk + (size_t)(t * 16 + g * 4 + i) * 256 + c * 2);
        }
    };
    auto write_x = [&](int buf) {
        _Float16* Ah = lds + buf * 16384;
        _Float16* Al = Ah + 4096;
#pragma unroll
        for (int u = 0; u < 2; ++u) {
            const int g = u * 2 + gsel;
            f16x8 h, lo;
#pragma unroll
            for (int i = 0; i < 4; ++i) {
                float a0 = xr[u * 4 + i].x, a1 = xr[u * 4 + i].y;
                _Float16 h0 = (_Float16)a0, h1 = (_Float16)a1;
                h[2 * i] = h0; h[2 * i + 1] = h1;
                lo[2 * i]     = (_Float16)((a0 - (float)h0) * LOSC);
                lo[2 * i + 1] = (_Float16)((a1 - (float)h1) * LOSC);
            }
            const int off = swz_f16(c, g);
            *(f16x8*)&Ah[off] = h;
            *(f16x8*)&Al[off] = lo;
        }
    };
    auto issue_W = [&](int t, int buf) {
        const int fb = fb0 + t * 32;
        _Float16* Bh = lds + buf * 16384 + 8192;
        _Float16* Bl = Bh + 4096;
#pragma unroll
        for (int q = 0; q < 2; ++q) {
            const int e0 = wave * 32 + q * 16;
            gload_lds16(Whi + (size_t)(e0 + e_ld) * 8192 + fb + goff, Bh + e0 * 32);
            gload_lds16(Wlo + (size_t)(e0 + e_ld) * 8192 + fb + goff, Bl + e0 * 32);
        }
    };

    // prologue
    issue_W(0, 0);
    load_x(0);
    write_x(0);
    __syncthreads();   // drains vmcnt (gload_lds) + lgkm (ds_write)

    for (int t = 0; t < KT; ++t) {
        const int buf = t & 1;
        if (t < KT - 1) { issue_W(t + 1, buf ^ 1); load_x(t + 1); }  // in flight over MFMA

        const _Float16* Ah = lds + buf * 16384;
        const _Float16* Al = Ah + 4096;
        const _Float16* Bh = Ah + 8192;
        const _Float16* Bl = Ah + 12288;
#pragma unroll
        for (int kk = 0; kk < 2; ++kk) {
            const int gk = kk * 2 + (lane >> 5);
            f16x8 ah[2], al[2], bh[2], bl[2];
#pragma unroll
            for (int i = 0; i < 2; ++i) {
                const int oa = swz_f16(wm * 64 + i * 32 + (lane & 31), gk);
                const int ob = swz_f16(wn * 64 + i * 32 + (lane & 31), gk);
                ah[i] = *(const f16x8*)&Ah[oa];
                al[i] = *(const f16x8*)&Al[oa];
                bh[i] = *(const f16x8*)&Bh[ob];
                bl[i] = *(const f16x8*)&Bl[ob];
            }
#pragma unroll
            for (int mi = 0; mi < 2; ++mi)
#pragma unroll
                for (int ni = 0; ni < 2; ++ni) {
                    acc1[mi][ni] = __builtin_amdgcn_mfma_f32_32x32x16_f16(ah[mi], bh[ni], acc1[mi][ni], 0, 0, 0);
                    acc2[mi][ni] = __builtin_amdgcn_mfma_f32_32x32x16_f16(ah[mi], bl[ni], acc2[mi][ni], 0, 0, 0);
                    acc2[mi][ni] = __builtin_amdgcn_mfma_f32_32x32x16_f16(al[mi], bh[ni], acc2[mi][ni], 0, 0, 0);
                }
        }
        if (t < KT - 1) write_x(buf ^ 1);   // buf^1 free since barrier t-1
        __syncthreads();                    // publishes writes + drains gload_lds
    }

    // epilogue: C/D layout (m74/m101): col=lane&31, row=(r&3)+8*(r>>2)+4*(lane>>5)
    float* outp = partials + ((size_t)kc * ROWS + (size_t)b * NCH) * NE2;
#pragma unroll
    for (int mi = 0; mi < 2; ++mi)
#pragma unroll
        for (int ni = 0; ni < 2; ++ni)
#pragma unroll
            for (int r = 0; r < 16; ++r) {
                const int rloc = (r & 3) + 8 * (r >> 2) + 4 * (lane >> 5);
                const int crow = wm * 64 + mi * 32 + rloc;
                const int e    = wn * 64 + ni * 32 + (lane & 31);
                outp[(size_t)crow * NE2 + e] = acc1[mi][ni][r] + acc2[mi][ni][r] * INV_LOSC;
            }
}

// ---------------------------------------------------------------------------
// Gate: reduce split-K partials, bias, softplus, exact kthvalue top-2 keep,
// masked softmax. Block = 2 rows x 128 experts.
// ---------------------------------------------------------------------------
__global__ __launch_bounds__(256)
void gate_kernel(const float* __restrict__ partials,
                 const float* __restrict__ bm,
                 const float* __restrict__ bn,
                 float* __restrict__ out)
{
    const int tid  = threadIdx.x;
    const int rl   = tid >> 7;
    const int e    = tid & 127;
    const int lane = tid & 63;
    const int row  = blockIdx.x * 2 + rl;

    const float* p = partials + (size_t)row * NE2 + e;
    float s = 0.f;
#pragma unroll
    for (int kc = 0; kc < KCH; ++kc)
        s += p[(size_t)kc * ROWS * NE2];

    __shared__ float spl[2][64];
    if (e >= NEXP) {
        float nz = s + bn[lane];
        spl[rl][lane] = fmaxf(nz, 0.f) + log1pf(expf(-fabsf(nz)));
    }
    __syncthreads();
    if (e < NEXP) {
        float g = s + bm[lane] + spl[rl][lane];

        float v  = g;
        float m1 = v;
#pragma unroll
        for (int o = 32; o > 0; o >>= 1) m1 = fmaxf(m1, __shfl_xor(m1, o));
        unsigned long long b1 = __ballot(v == m1);
        int l1 = __ffsll(b1) - 1;
        if (lane == l1) v = -INFINITY;
        float m2 = v;
#pragma unroll
        for (int o = 32; o > 0; o >>= 1) m2 = fmaxf(m2, __shfl_xor(m2, o));
        unsigned long long b2 = __ballot(v == m2);
        int l2 = __ffsll(b2) - 1;
        if (lane == l2) v = -INFINITY;
        float kth = v;
#pragma unroll
        for (int o = 32; o > 0; o >>= 1) kth = fmaxf(kth, __shfl_xor(kth, o));

        float ev  = (g > kth) ? expf(g - m1) : 0.f;
        float den = ev;
#pragma unroll
        for (int o = 32; o > 0; o >>= 1) den += __shfl_xor(den, o);
        out[(size_t)row * NEXP + lane] = ev / den;
    }
}

extern "C" void kernel_launch(void* const* d_in, const int* in_sizes, int n_in,
                              void* d_out, int out_size, void* d_ws, size_t ws_size,
                              hipStream_t stream)
{
    const float* x  = (const float*)d_in[0];
    const float* Wm = (const float*)d_in[1];
    const float* bm = (const float*)d_in[2];
    const float* Wn = (const float*)d_in[3];
    const float* bn = (const float*)d_in[4];
    float* out      = (float*)d_out;

    float*     partials = (float*)d_ws;                       // 32 MiB
    _Float16*  Whi      = (_Float16*)((char*)d_ws + WS_WHI);  // 2 MiB
    _Float16*  Wlo      = (_Float16*)((char*)d_ws + WS_WLO);  // 2 MiB

    wprep_kernel<<<1024, 256, 0, stream>>>(Wm, Wn, Whi, Wlo);
    gemm_kernel<<<512, 256, 0, stream>>>(x, Whi, Wlo, partials);
    gate_kernel<<<ROWS / 2, 256, 0, stream>>>(partials, bm, bn, out);
}